// Round 5
// baseline (450.875 us; speedup 1.0000x reference)
//
#include <hip/hip_runtime.h>
#include <hip/hip_bf16.h>

// Problem constants
#define BATCH 2
#define CIN   1024
#define NN    2048
#define HEADS 16
#define DHEAD 64
#define HDIM  1024
#define O3    3072
#define QSCALE 0.125f
#define QSZ ((size_t)BATCH * HEADS * NN * DHEAD)  // 4,194,304 elements

typedef unsigned short ushort_t;
typedef __attribute__((ext_vector_type(8))) short bf16x8;
typedef __attribute__((ext_vector_type(8))) unsigned short ushort8;
typedef __attribute__((ext_vector_type(4))) unsigned short ushort4v;
typedef __attribute__((ext_vector_type(16))) float f32x16;

__device__ inline ushort_t f2bf(float f) {
    unsigned u = __builtin_bit_cast(unsigned, f);
    unsigned r = u + 0x7fffu + ((u >> 16) & 1u);
    return (ushort_t)(r >> 16);
}
__device__ inline float bf2f(ushort_t h) {
    return __builtin_bit_cast(float, (unsigned)h << 16);
}
__device__ inline f32x16 mfma32(bf16x8 a, bf16x8 b, f32x16 c) {
    return __builtin_amdgcn_mfma_f32_32x32x16_bf16(a, b, c, 0, 0, 0);
}

union U4 { unsigned u[4]; bf16x8 v; };

// global -> LDS direct (16B per lane); LDS dest is wave-uniform base + lane*16
#define GLDS(gp, lp) __builtin_amdgcn_global_load_lds( \
    (__attribute__((address_space(1))) void*)(gp),     \
    (__attribute__((address_space(3))) void*)(lp), 16, 0, 0)

// ---------------- elementwise f32 -> bf16 hi/lo split ----------------
__global__ __launch_bounds__(256) void convert_split(const float* __restrict__ in,
                                                     ushort_t* __restrict__ hi,
                                                     ushort_t* __restrict__ lo,
                                                     int n8) {
    int t = blockIdx.x * 256 + threadIdx.x;
    if (t >= n8) return;
    size_t base = (size_t)t * 8;
    float4 a = *(const float4*)(in + base);
    float4 b = *(const float4*)(in + base + 4);
    float v[8] = {a.x, a.y, a.z, a.w, b.x, b.y, b.z, b.w};
    ushort8 hv, lv;
#pragma unroll
    for (int i = 0; i < 8; ++i) {
        ushort_t h = f2bf(v[i]);
        hv[i] = h;
        lv[i] = f2bf(v[i] - bf2f(h));
    }
    *(ushort8*)(hi + base) = hv;
    *(ushort8*)(lo + base) = lv;
}

// ------------- transpose + split: in f32 [B][CIN][NN] -> out hi/lo [B][NN][CIN] -------------
__global__ __launch_bounds__(256) void transpose_cvt(const float* __restrict__ in,
                                                     ushort_t* __restrict__ th,
                                                     ushort_t* __restrict__ tl) {
    __shared__ float T[32][33];
    const int b = blockIdx.z;
    const int n0 = blockIdx.x * 32, c0 = blockIdx.y * 32;
    const int t = threadIdx.x;
    const int r = t >> 3, q = t & 7;
    float4 v = *(const float4*)(in + ((size_t)b * CIN + c0 + r) * NN + n0 + q * 4);
    T[r][q * 4 + 0] = v.x; T[r][q * 4 + 1] = v.y;
    T[r][q * 4 + 2] = v.z; T[r][q * 4 + 3] = v.w;
    __syncthreads();
    ushort4v hv, lv;
#pragma unroll
    for (int i = 0; i < 4; ++i) {
        float f = T[q * 4 + i][r];
        ushort_t h = f2bf(f);
        hv[i] = h;
        lv[i] = f2bf(f - bf2f(h));
    }
    size_t o = ((size_t)b * NN + n0 + r) * CIN + c0 + q * 4;
    *(ushort4v*)(th + o) = hv;
    *(ushort4v*)(tl + o) = lv;
}

// ---------------- MFMA split-bf16 GEMM ----------------
// C[b,m,n] = sum_k (Ah+Al)[m,k] * (Bth+Btl)[b,n,k]  (3-term split product)
// MODE 0: QKV epilogue (writes Qh/Ql/Kh/Kl transposed-scaled, Vh/Vl channel-major)
// MODE 1: f32 out + bias
template<int MODE>
__global__ __launch_bounds__(256, 3) void gemm_mfma(
    const ushort_t* __restrict__ Ah, const ushort_t* __restrict__ Al,
    const ushort_t* __restrict__ Bth, const ushort_t* __restrict__ Btl,
    const float* __restrict__ bias, float* __restrict__ outF,
    ushort_t* __restrict__ Qh, ushort_t* __restrict__ Ql,
    ushort_t* __restrict__ Kh, ushort_t* __restrict__ Kl,
    ushort_t* __restrict__ Vh, ushort_t* __restrict__ Vl) {

    __shared__ __align__(16) ushort_t lsAh[4096], lsAl[4096], lsBh[4096], lsBl[4096];

    const int b  = blockIdx.z;
    const int n0 = blockIdx.x * 128;
    const int m0 = blockIdx.y * 128;
    const int tid = threadIdx.x;
    const int wave = tid >> 6, lane = tid & 63;
    const int l31 = lane & 31, hi5 = lane >> 5;
    const int wr = wave >> 1, wc = wave & 1;

    // ---- staging addresses (pre-swizzled global source; linear LDS dest) ----
    const int srow = lane >> 2;
    const int kswz = 8 * ((lane & 3) ^ ((lane >> 3) & 3));
    const ushort_t* gAh = Ah  + (size_t)(m0 + wave * 16 + srow) * CIN + kswz;
    const ushort_t* gAl = Al  + (size_t)(m0 + wave * 16 + srow) * CIN + kswz;
    const ushort_t* gBh = Bth + ((size_t)b * NN + n0 + wave * 16 + srow) * CIN + kswz;
    const ushort_t* gBl = Btl + ((size_t)b * NN + n0 + wave * 16 + srow) * CIN + kswz;
    ushort_t* dAh = lsAh + wave * 512;
    ushort_t* dAl = lsAl + wave * 512;
    ushort_t* dBh = lsBh + wave * 512;
    ushort_t* dBl = lsBl + wave * 512;

    // ---- ds_read byte offsets (swizzle-matched) ----
    const int rswz = ((l31 >> 1) & 3) * 8;
    int offA[2][2], offB[2][2];
#pragma unroll
    for (int f = 0; f < 2; ++f)
#pragma unroll
        for (int kh = 0; kh < 2; ++kh) {
            offA[f][kh] = (wr * 64 + f * 32 + l31) * 64 + ((kh * 16 + hi5 * 8) ^ rswz) * 2;
            offB[f][kh] = (wc * 64 + f * 32 + l31) * 64 + ((kh * 16 + hi5 * 8) ^ rswz) * 2;
        }

    f32x16 acc[2][2];
#pragma unroll
    for (int i = 0; i < 2; ++i)
#pragma unroll
        for (int j = 0; j < 2; ++j)
#pragma unroll
            for (int r = 0; r < 16; ++r) acc[i][j][r] = 0.f;

    for (int k0 = 0; k0 < CIN; k0 += 32) {
        __syncthreads();   // previous compute done with LDS
        GLDS(gAh + k0,            dAh);
        GLDS(gAh + 64 * CIN + k0, dAh + 2048);
        GLDS(gAl + k0,            dAl);
        GLDS(gAl + 64 * CIN + k0, dAl + 2048);
        GLDS(gBh + k0,            dBh);
        GLDS(gBh + 64 * CIN + k0, dBh + 2048);
        GLDS(gBl + k0,            dBl);
        GLDS(gBl + 64 * CIN + k0, dBl + 2048);
        __syncthreads();   // compiler drains vmcnt before barrier
#pragma unroll
        for (int kh = 0; kh < 2; ++kh) {
            bf16x8 a_h[2], a_l[2], b_h[2], b_l[2];
#pragma unroll
            for (int f = 0; f < 2; ++f) {
                a_h[f] = *(const bf16x8*)((const char*)lsAh + offA[f][kh]);
                a_l[f] = *(const bf16x8*)((const char*)lsAl + offA[f][kh]);
                b_h[f] = *(const bf16x8*)((const char*)lsBh + offB[f][kh]);
                b_l[f] = *(const bf16x8*)((const char*)lsBl + offB[f][kh]);
            }
#pragma unroll
            for (int fi = 0; fi < 2; ++fi)
#pragma unroll
                for (int fj = 0; fj < 2; ++fj) {
                    acc[fi][fj] = mfma32(a_l[fi], b_h[fj], acc[fi][fj]);
                    acc[fi][fj] = mfma32(a_h[fi], b_l[fj], acc[fi][fj]);
                    acc[fi][fj] = mfma32(a_h[fi], b_h[fj], acc[fi][fj]);
                }
        }
    }

    const int nn = n0 + wc * 64 + l31;

    if constexpr (MODE == 0) {
        const int region = m0 >> 10;  // 0=Q 1=K 2=V (uniform per block)
        if (region < 2) {
            const float scale = (region == 0) ? QSCALE : 1.0f;
            ushort_t* H = (region == 0) ? Qh : Kh;
            ushort_t* L = (region == 0) ? Ql : Kl;
            const int head = ((m0 & 1023) >> 6) + wr;
            const size_t bh_base = (size_t)(b * HEADS + head) * NN;
#pragma unroll
            for (int fj = 0; fj < 2; ++fj) {
                const size_t rowb = (bh_base + nn + fj * 32) * DHEAD;
#pragma unroll
                for (int fi = 0; fi < 2; ++fi) {
                    const int d0 = fi * 32 + 4 * hi5;
#pragma unroll
                    for (int g = 0; g < 4; ++g) {
                        ushort4v hv, lv;
#pragma unroll
                        for (int i = 0; i < 4; ++i) {
                            float f = acc[fi][fj][4 * g + i] * scale;
                            ushort_t h2 = f2bf(f);
                            hv[i] = h2;
                            lv[i] = f2bf(f - bf2f(h2));
                        }
                        *(ushort4v*)(H + rowb + d0 + 8 * g) = hv;
                        *(ushort4v*)(L + rowb + d0 + 8 * g) = lv;
                    }
                }
            }
        } else {
            const int ch0 = (m0 - 2048) + wr * 64;
#pragma unroll
            for (int fi = 0; fi < 2; ++fi)
#pragma unroll
                for (int fj = 0; fj < 2; ++fj)
#pragma unroll
                    for (int r = 0; r < 16; ++r) {
                        const int ch = ch0 + fi * 32 + (r & 3) + 8 * (r >> 2) + 4 * hi5;
                        const size_t idx = ((size_t)b * HDIM + ch) * NN + nn + fj * 32;
                        float f = acc[fi][fj][r];
                        ushort_t h2 = f2bf(f);
                        Vh[idx] = h2;
                        Vl[idx] = f2bf(f - bf2f(h2));
                    }
        }
    } else {
#pragma unroll
        for (int fi = 0; fi < 2; ++fi)
#pragma unroll
            for (int fj = 0; fj < 2; ++fj)
#pragma unroll
                for (int r = 0; r < 16; ++r) {
                    const int mrow = m0 + wr * 64 + fi * 32 + (r & 3) + 8 * (r >> 2) + 4 * hi5;
                    outF[((size_t)b * CIN + mrow) * NN + nn + fj * 32] =
                        acc[fi][fj][r] + bias[mrow];
                }
    }
}

// ---------------- MFMA flash attention, split-KV across 4 waves ----------------
// Block = 32 queries; wave w scans keys [w*512, (w+1)*512); LDS combine.
// bh-clustering XCD swizzle: 4 heads per XCD -> K/V working set fits one L2.
__global__ __launch_bounds__(256, 4) void attn_mfma(
    const ushort_t* __restrict__ Qh, const ushort_t* __restrict__ Ql,
    const ushort_t* __restrict__ Kh, const ushort_t* __restrict__ Kl,
    const ushort_t* __restrict__ Vh, const ushort_t* __restrict__ Vl,
    ushort_t* __restrict__ aoth, ushort_t* __restrict__ aotl) {
    // swizzle: 2048 blocks = 8 xcd-slots x 4 bh x 64 qtiles
    const int Lid = blockIdx.x;
    const int slot = Lid & 7, idx = Lid >> 3;
    const int bh = slot * 4 + (idx >> 6);
    const int qt = idx & 63;
    const int b = bh >> 4, h = bh & 15;
    const int q0 = qt * 32;

    const int wave = threadIdx.x >> 6;
    const int lane = threadIdx.x & 63;
    const int l31 = lane & 31;
    const int hi5 = lane >> 5;

    __shared__ float mS[4][64], lS[4][64];
    __shared__ __align__(16) float oS[4][8][64][4];  // [wave][rquad][lane][4]

    bf16x8 qfh[4], qfl[4];
    {
        const ushort_t* qb  = Qh + ((size_t)bh * NN + q0 + l31) * DHEAD + hi5 * 8;
        const ushort_t* ql_ = Ql + ((size_t)bh * NN + q0 + l31) * DHEAD + hi5 * 8;
#pragma unroll
        for (int c = 0; c < 4; ++c) {
            qfh[c] = *(const bf16x8*)(qb + c * 16);
            qfl[c] = *(const bf16x8*)(ql_ + c * 16);
        }
    }

    f32x16 o0, o1, zz;
#pragma unroll
    for (int r = 0; r < 16; ++r) { o0[r] = 0.f; o1[r] = 0.f; zz[r] = 0.f; }
    float m = -1e30f, l = 0.f;

    const ushort_t* kbh = Kh + ((size_t)bh * NN + l31) * DHEAD + hi5 * 8;
    const ushort_t* kbl = Kl + ((size_t)bh * NN + l31) * DHEAD + hi5 * 8;
    const ushort_t* vbh = Vh + (size_t)bh * DHEAD * NN + hi5 * 8;
    const ushort_t* vbl = Vl + (size_t)bh * DHEAD * NN + hi5 * 8;

    const int jbase = wave * (NN / 4);

#pragma unroll 2
    for (int jt = 0; jt < 16; ++jt) {
        const int j0_ = jbase + jt * 32;
        // K tile
        bf16x8 kh_[4], kl_[4];
#pragma unroll
        for (int c = 0; c < 4; ++c) {
            kh_[c] = *(const bf16x8*)(kbh + (size_t)j0_ * DHEAD + c * 16);
            kl_[c] = *(const bf16x8*)(kbl + (size_t)j0_ * DHEAD + c * 16);
        }
        // V tile
        bf16x8 vh_[4], vl_[4];
#pragma unroll
        for (int jc = 0; jc < 2; ++jc)
#pragma unroll
            for (int dt = 0; dt < 2; ++dt) {
                size_t voff = (size_t)(dt * 32 + l31) * NN + j0_ + jc * 16;
                vh_[2 * jc + dt] = *(const bf16x8*)(vbh + voff);
                vl_[2 * jc + dt] = *(const bf16x8*)(vbl + voff);
            }

        // QK^T: two independent 6-deep chains
        f32x16 sA = mfma32(kh_[0], qfh[0], zz);
        sA = mfma32(kl_[0], qfh[0], sA);
        sA = mfma32(kh_[0], qfl[0], sA);
        sA = mfma32(kh_[1], qfh[1], sA);
        sA = mfma32(kl_[1], qfh[1], sA);
        sA = mfma32(kh_[1], qfl[1], sA);
        f32x16 sB = mfma32(kh_[2], qfh[2], zz);
        sB = mfma32(kl_[2], qfh[2], sB);
        sB = mfma32(kh_[2], qfl[2], sB);
        sB = mfma32(kh_[3], qfh[3], sB);
        sB = mfma32(kl_[3], qfh[3], sB);
        sB = mfma32(kh_[3], qfl[3], sB);
        f32x16 s;
#pragma unroll
        for (int r = 0; r < 16; ++r) s[r] = sA[r] + sB[r];

        float tmA = fmaxf(fmaxf(fmaxf(s[0], s[1]), fmaxf(s[2], s[3])),
                          fmaxf(fmaxf(s[4], s[5]), fmaxf(s[6], s[7])));
        float tmB = fmaxf(fmaxf(fmaxf(s[8], s[9]), fmaxf(s[10], s[11])),
                          fmaxf(fmaxf(s[12], s[13]), fmaxf(s[14], s[15])));
        float tmax = fmaxf(tmA, tmB);
        tmax = fmaxf(tmax, __shfl_xor(tmax, 32));
        if (!__all(tmax - m <= 8.0f)) {
            float mn = fmaxf(m, tmax);
            float corr = __expf(m - mn);
            l *= corr;
#pragma unroll
            for (int r = 0; r < 16; ++r) { o0[r] *= corr; o1[r] *= corr; }
            m = mn;
        }
        float ps = 0.f;
#pragma unroll
        for (int r = 0; r < 16; ++r) {
            s[r] = __expf(s[r] - m);
            ps += s[r];
        }
        l += ps + __shfl_xor(ps, 32);

        // pack + blend-shuffle P redistribution; PV
#pragma unroll
        for (int jc = 0; jc < 2; ++jc) {
            ushort_t h0 = f2bf(s[8 * jc + 0]), h1 = f2bf(s[8 * jc + 1]);
            ushort_t h2 = f2bf(s[8 * jc + 2]), h3 = f2bf(s[8 * jc + 3]);
            ushort_t h4 = f2bf(s[8 * jc + 4]), h5 = f2bf(s[8 * jc + 5]);
            ushort_t h6 = f2bf(s[8 * jc + 6]), h7 = f2bf(s[8 * jc + 7]);
            unsigned P0 = (unsigned)h0 | ((unsigned)h1 << 16);
            unsigned P1 = (unsigned)h2 | ((unsigned)h3 << 16);
            unsigned P2 = (unsigned)h4 | ((unsigned)h5 << 16);
            unsigned P3 = (unsigned)h6 | ((unsigned)h7 << 16);
            unsigned L0 = (unsigned)f2bf(s[8 * jc + 0] - bf2f(h0)) |
                          ((unsigned)f2bf(s[8 * jc + 1] - bf2f(h1)) << 16);
            unsigned L1 = (unsigned)f2bf(s[8 * jc + 2] - bf2f(h2)) |
                          ((unsigned)f2bf(s[8 * jc + 3] - bf2f(h3)) << 16);
            unsigned L2 = (unsigned)f2bf(s[8 * jc + 4] - bf2f(h4)) |
                          ((unsigned)f2bf(s[8 * jc + 5] - bf2f(h5)) << 16);
            unsigned L3 = (unsigned)f2bf(s[8 * jc + 6] - bf2f(h6)) |
                          ((unsigned)f2bf(s[8 * jc + 7] - bf2f(h7)) << 16);
            unsigned ta = hi5 ? P0 : P2, tb = hi5 ? P1 : P3;
            unsigned ua = hi5 ? L0 : L2, ub = hi5 ? L1 : L3;
            unsigned sa = __shfl_xor((int)ta, 32), sb = __shfl_xor((int)tb, 32);
            unsigned va = __shfl_xor((int)ua, 32), vb = __shfl_xor((int)ub, 32);
            U4 th, tl;
            th.u[0] = hi5 ? sa : P0; th.u[1] = hi5 ? sb : P1;
            th.u[2] = hi5 ? P2 : sa; th.u[3] = hi5 ? P3 : sb;
            tl.u[0] = hi5 ? va : L0; tl.u[1] = hi5 ? vb : L1;
            tl.u[2] = hi5 ? L2 : va; tl.u[3] = hi5 ? L3 : vb;
            bf16x8 pBh = th.v, pBl = tl.v;
            o0 = mfma32(vh_[2 * jc + 0], pBh, o0);
            o0 = mfma32(vh_[2 * jc + 0], pBl, o0);
            o0 = mfma32(vl_[2 * jc + 0], pBh, o0);
            o1 = mfma32(vh_[2 * jc + 1], pBh, o1);
            o1 = mfma32(vh_[2 * jc + 1], pBl, o1);
            o1 = mfma32(vl_[2 * jc + 1], pBh, o1);
        }
    }

    // ---- cross-wave combine via LDS ----
    mS[wave][lane] = m;
    lS[wave][lane] = l;
#pragma unroll
    for (int rq = 0; rq < 4; ++rq) {
        float4 v0 = {o0[4 * rq + 0], o0[4 * rq + 1], o0[4 * rq + 2], o0[4 * rq + 3]};
        *(float4*)&oS[wave][rq][lane][0] = v0;
        float4 v1 = {o1[4 * rq + 0], o1[4 * rq + 1], o1[4 * rq + 2], o1[4 * rq + 3]};
        *(float4*)&oS[wave][4 + rq][lane][0] = v1;
    }
    __syncthreads();

    const float m0_ = mS[0][lane], m1_ = mS[1][lane];
    const float m2_ = mS[2][lane], m3_ = mS[3][lane];
    const float M = fmaxf(fmaxf(m0_, m1_), fmaxf(m2_, m3_));
    const float w0 = __expf(m0_ - M), w1 = __expf(m1_ - M);
    const float w2 = __expf(m2_ - M), w3 = __expf(m3_ - M);
    const float Lsum = lS[0][lane] * w0 + lS[1][lane] * w1 +
                       lS[2][lane] * w2 + lS[3][lane] * w3;
    const float invL = 1.0f / Lsum;

    const size_t rowb = ((size_t)b * NN + q0 + l31) * HDIM + h * DHEAD;
#pragma unroll
    for (int t = 0; t < 2; ++t) {
        const int rq = 2 * wave + t;          // 0..7
        float4 a0 = *(const float4*)&oS[0][rq][lane][0];
        float4 a1 = *(const float4*)&oS[1][rq][lane][0];
        float4 a2 = *(const float4*)&oS[2][rq][lane][0];
        float4 a3 = *(const float4*)&oS[3][rq][lane][0];
        float c[4] = {
            (a0.x * w0 + a1.x * w1 + a2.x * w2 + a3.x * w3) * invL,
            (a0.y * w0 + a1.y * w1 + a2.y * w2 + a3.y * w3) * invL,
            (a0.z * w0 + a1.z * w1 + a2.z * w2 + a3.z * w3) * invL,
            (a0.w * w0 + a1.w * w1 + a2.w * w2 + a3.w * w3) * invL};
        const int dt = rq >> 2, g = rq & 3;
        ushort4v hv, lv;
#pragma unroll
        for (int i = 0; i < 4; ++i) {
            ushort_t h2 = f2bf(c[i]);
            hv[i] = h2;
            lv[i] = f2bf(c[i] - bf2f(h2));
        }
        size_t o = rowb + dt * 32 + 8 * g + 4 * hi5;
        *(ushort4v*)(aoth + o) = hv;
        *(ushort4v*)(aotl + o) = lv;
    }
}

// ---------------- launch ----------------
extern "C" void kernel_launch(void* const* d_in, const int* in_sizes, int n_in,
                              void* d_out, int out_size, void* d_ws, size_t ws_size,
                              hipStream_t stream) {
    const float* x     = (const float*)d_in[0];
    const float* w_qkv = (const float*)d_in[1];
    const float* w_out = (const float*)d_in[2];
    const float* b_out = (const float*)d_in[3];
    float* out = (float*)d_out;

    ushort_t* ws_u = (ushort_t*)d_ws;
    // persistent through attention:
    ushort_t* Qh = ws_u;
    ushort_t* Ql = Qh + QSZ;
    ushort_t* Kh = Ql + QSZ;
    ushort_t* Kl = Kh + QSZ;
    ushort_t* Vh = Kl + QSZ;
    ushort_t* Vl = Vh + QSZ;
    // shared region (16.78 MB): wq hi/lo (phase A), then aot hi/lo (phase B)
    ushort_t* shared_u = ws_u + 6 * QSZ;
    ushort_t* wqh = shared_u;
    ushort_t* wql = wqh + (size_t)O3 * CIN;
    ushort_t* aoth = shared_u;
    ushort_t* aotl = aoth + (size_t)BATCH * NN * HDIM;
    // wo hi/lo into dead Q region (phase B)
    ushort_t* woh = ws_u;
    ushort_t* wol = woh + (size_t)CIN * HDIM;
    // xt scratch lives inside d_out (exactly out_size bytes), dead before final GEMM
    ushort_t* xth = (ushort_t*)d_out;
    ushort_t* xtl = xth + (size_t)BATCH * NN * CIN;

    if (ws_size < (6 * QSZ + 2 * (size_t)BATCH * NN * CIN) * sizeof(ushort_t)) return;

    // 1) weight + input conversions
    convert_split<<<1536, 256, 0, stream>>>(w_qkv, wqh, wql, O3 * CIN / 8);
    transpose_cvt<<<dim3(NN / 32, CIN / 32, BATCH), 256, 0, stream>>>(x, xth, xtl);

    // 2) QKV projection (MFMA split-bf16) -> Q/K/V hi/lo
    gemm_mfma<0><<<dim3(NN / 128, O3 / 128, BATCH), 256, 0, stream>>>(
        wqh, wql, xth, xtl, nullptr, nullptr, Qh, Ql, Kh, Kl, Vh, Vl);

    // 3) flash attention (split-KV, 2048 blocks) -> aot hi/lo [b][n][ch]
    attn_mfma<<<dim3(BATCH * HEADS * (NN / 32)), 256, 0, stream>>>(
        Qh, Ql, Kh, Kl, Vh, Vl, aoth, aotl);

    // 4) w_out conversion into dead Q region
    convert_split<<<512, 256, 0, stream>>>(w_out, woh, wol, CIN * HDIM / 8);

    // 5) output projection (MFMA split-bf16) + bias -> out f32 (overwrites xt)
    gemm_mfma<1><<<dim3(NN / 128, HDIM / 128, BATCH), 256, 0, stream>>>(
        woh, wol, aoth, aotl, b_out, out, nullptr, nullptr, nullptr, nullptr,
        nullptr, nullptr);
}

// Round 6
// 268.965 us; speedup vs baseline: 1.6763x; 1.6763x over previous
//
#include <hip/hip_runtime.h>
#include <hip/hip_bf16.h>

// Problem constants
#define BATCH 2
#define CIN   1024
#define NN    2048
#define HEADS 16
#define DHEAD 64
#define HDIM  1024
#define O3    3072
#define QSCALE 0.125f
#define QSZ ((size_t)BATCH * HEADS * NN * DHEAD)  // 4,194,304 elements

typedef unsigned short ushort_t;
typedef __attribute__((ext_vector_type(8))) short bf16x8;
typedef __attribute__((ext_vector_type(8))) unsigned short ushort8;
typedef __attribute__((ext_vector_type(4))) unsigned short ushort4v;
typedef __attribute__((ext_vector_type(16))) float f32x16;

__device__ inline ushort_t f2bf(float f) {
    unsigned u = __builtin_bit_cast(unsigned, f);
    unsigned r = u + 0x7fffu + ((u >> 16) & 1u);
    return (ushort_t)(r >> 16);
}
__device__ inline float bf2f(ushort_t h) {
    return __builtin_bit_cast(float, (unsigned)h << 16);
}
__device__ inline f32x16 mfma32(bf16x8 a, bf16x8 b, f32x16 c) {
    return __builtin_amdgcn_mfma_f32_32x32x16_bf16(a, b, c, 0, 0, 0);
}

union U4 { unsigned u[4]; bf16x8 v; };

// global -> LDS direct (16B per lane); LDS dest is wave-uniform base + lane*16
#define GLDS(gp, lp) __builtin_amdgcn_global_load_lds( \
    (__attribute__((address_space(1))) void*)(gp),     \
    (__attribute__((address_space(3))) void*)(lp), 16, 0, 0)

// ---------------- elementwise f32 -> bf16 hi/lo split ----------------
__global__ __launch_bounds__(256) void convert_split(const float* __restrict__ in,
                                                     ushort_t* __restrict__ hi,
                                                     ushort_t* __restrict__ lo,
                                                     int n8) {
    int t = blockIdx.x * 256 + threadIdx.x;
    if (t >= n8) return;
    size_t base = (size_t)t * 8;
    float4 a = *(const float4*)(in + base);
    float4 b = *(const float4*)(in + base + 4);
    float v[8] = {a.x, a.y, a.z, a.w, b.x, b.y, b.z, b.w};
    ushort8 hv, lv;
#pragma unroll
    for (int i = 0; i < 8; ++i) {
        ushort_t h = f2bf(v[i]);
        hv[i] = h;
        lv[i] = f2bf(v[i] - bf2f(h));
    }
    *(ushort8*)(hi + base) = hv;
    *(ushort8*)(lo + base) = lv;
}

// ------------- transpose + split: in f32 [B][CIN][NN] -> out hi/lo [B][NN][CIN] -------------
__global__ __launch_bounds__(256) void transpose_cvt(const float* __restrict__ in,
                                                     ushort_t* __restrict__ th,
                                                     ushort_t* __restrict__ tl) {
    __shared__ float T[32][33];
    const int b = blockIdx.z;
    const int n0 = blockIdx.x * 32, c0 = blockIdx.y * 32;
    const int t = threadIdx.x;
    const int r = t >> 3, q = t & 7;
    float4 v = *(const float4*)(in + ((size_t)b * CIN + c0 + r) * NN + n0 + q * 4);
    T[r][q * 4 + 0] = v.x; T[r][q * 4 + 1] = v.y;
    T[r][q * 4 + 2] = v.z; T[r][q * 4 + 3] = v.w;
    __syncthreads();
    ushort4v hv, lv;
#pragma unroll
    for (int i = 0; i < 4; ++i) {
        float f = T[q * 4 + i][r];
        ushort_t h = f2bf(f);
        hv[i] = h;
        lv[i] = f2bf(f - bf2f(h));
    }
    size_t o = ((size_t)b * NN + n0 + r) * CIN + c0 + q * 4;
    *(ushort4v*)(th + o) = hv;
    *(ushort4v*)(tl + o) = lv;
}

// ---------------- MFMA split-bf16 GEMM ----------------
// MODE 0: QKV epilogue. Q: [bh][n][64] plain. K: same but 16B-granules XOR-swizzled
// by (row&7) within each 128B row. V: [b*1024+ch][n] with n's within-64 granule
// XOR-swizzled by (ch&7). These images are what attn's GLDS stages linearly.
// MODE 1: f32 out + bias
template<int MODE>
__global__ __launch_bounds__(256, 3) void gemm_mfma(
    const ushort_t* __restrict__ Ah, const ushort_t* __restrict__ Al,
    const ushort_t* __restrict__ Bth, const ushort_t* __restrict__ Btl,
    const float* __restrict__ bias, float* __restrict__ outF,
    ushort_t* __restrict__ Qh, ushort_t* __restrict__ Ql,
    ushort_t* __restrict__ Kh, ushort_t* __restrict__ Kl,
    ushort_t* __restrict__ Vh, ushort_t* __restrict__ Vl) {

    __shared__ __align__(16) ushort_t lsAh[4096], lsAl[4096], lsBh[4096], lsBl[4096];

    const int b  = blockIdx.z;
    const int n0 = blockIdx.x * 128;
    const int m0 = blockIdx.y * 128;
    const int tid = threadIdx.x;
    const int wave = tid >> 6, lane = tid & 63;
    const int l31 = lane & 31, hi5 = lane >> 5;
    const int wr = wave >> 1, wc = wave & 1;

    const int srow = lane >> 2;
    const int kswz = 8 * ((lane & 3) ^ ((lane >> 3) & 3));
    const ushort_t* gAh = Ah  + (size_t)(m0 + wave * 16 + srow) * CIN + kswz;
    const ushort_t* gAl = Al  + (size_t)(m0 + wave * 16 + srow) * CIN + kswz;
    const ushort_t* gBh = Bth + ((size_t)b * NN + n0 + wave * 16 + srow) * CIN + kswz;
    const ushort_t* gBl = Btl + ((size_t)b * NN + n0 + wave * 16 + srow) * CIN + kswz;
    ushort_t* dAh = lsAh + wave * 512;
    ushort_t* dAl = lsAl + wave * 512;
    ushort_t* dBh = lsBh + wave * 512;
    ushort_t* dBl = lsBl + wave * 512;

    const int rswz = ((l31 >> 1) & 3) * 8;
    int offA[2][2], offB[2][2];
#pragma unroll
    for (int f = 0; f < 2; ++f)
#pragma unroll
        for (int kh = 0; kh < 2; ++kh) {
            offA[f][kh] = (wr * 64 + f * 32 + l31) * 64 + ((kh * 16 + hi5 * 8) ^ rswz) * 2;
            offB[f][kh] = (wc * 64 + f * 32 + l31) * 64 + ((kh * 16 + hi5 * 8) ^ rswz) * 2;
        }

    f32x16 acc[2][2];
#pragma unroll
    for (int i = 0; i < 2; ++i)
#pragma unroll
        for (int j = 0; j < 2; ++j)
#pragma unroll
            for (int r = 0; r < 16; ++r) acc[i][j][r] = 0.f;

    for (int k0 = 0; k0 < CIN; k0 += 32) {
        __syncthreads();
        GLDS(gAh + k0,            dAh);
        GLDS(gAh + 64 * CIN + k0, dAh + 2048);
        GLDS(gAl + k0,            dAl);
        GLDS(gAl + 64 * CIN + k0, dAl + 2048);
        GLDS(gBh + k0,            dBh);
        GLDS(gBh + 64 * CIN + k0, dBh + 2048);
        GLDS(gBl + k0,            dBl);
        GLDS(gBl + 64 * CIN + k0, dBl + 2048);
        __syncthreads();
#pragma unroll
        for (int kh = 0; kh < 2; ++kh) {
            bf16x8 a_h[2], a_l[2], b_h[2], b_l[2];
#pragma unroll
            for (int f = 0; f < 2; ++f) {
                a_h[f] = *(const bf16x8*)((const char*)lsAh + offA[f][kh]);
                a_l[f] = *(const bf16x8*)((const char*)lsAl + offA[f][kh]);
                b_h[f] = *(const bf16x8*)((const char*)lsBh + offB[f][kh]);
                b_l[f] = *(const bf16x8*)((const char*)lsBl + offB[f][kh]);
            }
#pragma unroll
            for (int fi = 0; fi < 2; ++fi)
#pragma unroll
                for (int fj = 0; fj < 2; ++fj) {
                    acc[fi][fj] = mfma32(a_l[fi], b_h[fj], acc[fi][fj]);
                    acc[fi][fj] = mfma32(a_h[fi], b_l[fj], acc[fi][fj]);
                    acc[fi][fj] = mfma32(a_h[fi], b_h[fj], acc[fi][fj]);
                }
        }
    }

    const int nn = n0 + wc * 64 + l31;

    if constexpr (MODE == 0) {
        const int region = m0 >> 10;  // 0=Q 1=K 2=V (uniform per block)
        if (region < 2) {
            const float scale = (region == 0) ? QSCALE : 1.0f;
            ushort_t* H = (region == 0) ? Qh : Kh;
            ushort_t* L = (region == 0) ? Ql : Kl;
            const int head = ((m0 & 1023) >> 6) + wr;
            const size_t bh_base = (size_t)(b * HEADS + head) * NN;
#pragma unroll
            for (int fj = 0; fj < 2; ++fj) {
                const size_t rowb = (bh_base + nn + fj * 32) * DHEAD;
#pragma unroll
                for (int fi = 0; fi < 2; ++fi) {
#pragma unroll
                    for (int g = 0; g < 4; ++g) {
                        ushort4v hv, lv;
#pragma unroll
                        for (int i = 0; i < 4; ++i) {
                            float f = acc[fi][fj][4 * g + i] * scale;
                            ushort_t h2 = f2bf(f);
                            hv[i] = h2;
                            lv[i] = f2bf(f - bf2f(h2));
                        }
                        // K gets granule swizzle ^(row&7); row&7 == l31&7
                        const int e = (region == 1)
                            ? (((fi * 4 + g) ^ (l31 & 7)) * 8 + 4 * hi5)
                            : (fi * 32 + 4 * hi5 + 8 * g);
                        *(ushort4v*)(H + rowb + e) = hv;
                        *(ushort4v*)(L + rowb + e) = lv;
                    }
                }
            }
        } else {
            const int ch0 = (m0 - 2048) + wr * 64;
#pragma unroll
            for (int fi = 0; fi < 2; ++fi)
#pragma unroll
                for (int fj = 0; fj < 2; ++fj)
#pragma unroll
                    for (int r = 0; r < 16; ++r) {
                        const int ch = ch0 + fi * 32 + (r & 3) + 8 * (r >> 2) + 4 * hi5;
                        // n granule swizzle within 64-group by ch&7
                        const int g6 = (fj * 4 + (l31 >> 3)) ^ ((r & 3) + 4 * hi5);
                        const int n_ = n0 + wc * 64 + g6 * 8 + (l31 & 7);
                        const size_t idx = ((size_t)b * HDIM + ch) * NN + n_;
                        float f = acc[fi][fj][r];
                        ushort_t h2 = f2bf(f);
                        Vh[idx] = h2;
                        Vl[idx] = f2bf(f - bf2f(h2));
                    }
        }
    } else {
#pragma unroll
        for (int fi = 0; fi < 2; ++fi)
#pragma unroll
            for (int fj = 0; fj < 2; ++fj)
#pragma unroll
                for (int r = 0; r < 16; ++r) {
                    const int mrow = m0 + wr * 64 + fi * 32 + (r & 3) + 8 * (r >> 2) + 4 * hi5;
                    outF[((size_t)b * CIN + mrow) * NN + nn + fj * 32] =
                        acc[fi][fj][r] + bias[mrow];
                }
    }
}

// ---------------- MFMA flash attention: LDS-staged K/V, double-buffered ----------------
// Block = 128 queries (4 waves x 32q); loop over 64-key tiles; all waves share
// the staged tile. K tile [64 keys][64d], V tile [64d][64 keys], both with
// granule^(row&7) swizzle (pre-applied in global by gemm_mfma<0>).
__global__ __launch_bounds__(256, 2) void attn_mfma(
    const ushort_t* __restrict__ Qh, const ushort_t* __restrict__ Ql,
    const ushort_t* __restrict__ Kh, const ushort_t* __restrict__ Kl,
    const ushort_t* __restrict__ Vh, const ushort_t* __restrict__ Vl,
    ushort_t* __restrict__ aoth, ushort_t* __restrict__ aotl) {
    // grid 512 = 8 xcd-slots x 4 bh x 16 qtiles (K/V of 4 heads ~ one L2)
    const int Lid = blockIdx.x;
    const int slot = Lid & 7, rest = Lid >> 3;
    const int bh = slot * 4 + (rest >> 4);
    const int qt = rest & 15;
    const int b = bh >> 4, h = bh & 15;
    const int wave = threadIdx.x >> 6;
    const int lane = threadIdx.x & 63;
    const int l31 = lane & 31;
    const int hi5 = lane >> 5;
    const int r7 = l31 & 7;
    const int q0 = qt * 128 + wave * 32;

    __shared__ __align__(16) ushort_t lsKh[2][4096], lsKl[2][4096];
    __shared__ __align__(16) ushort_t lsVh[2][4096], lsVl[2][4096];

    // Q fragments (8 one-time gathers)
    bf16x8 qfh[4], qfl[4];
    {
        const ushort_t* qb  = Qh + ((size_t)bh * NN + q0 + l31) * DHEAD + hi5 * 8;
        const ushort_t* qlb = Ql + ((size_t)bh * NN + q0 + l31) * DHEAD + hi5 * 8;
#pragma unroll
        for (int c = 0; c < 4; ++c) {
            qfh[c] = *(const bf16x8*)(qb + c * 16);
            qfl[c] = *(const bf16x8*)(qlb + c * 16);
        }
    }

    // staging: wave 0->Kh 1->Kl 2->Vh 3->Vl; 8 GLDS x 1KB each, fully coalesced
    const size_t kbase = (size_t)bh * NN * DHEAD;
    const size_t vbase = (size_t)bh * DHEAD * NN;
    const ushort_t* gsel = (wave == 0) ? Kh + kbase
                         : (wave == 1) ? Kl + kbase
                         : (wave == 2) ? Vh + vbase
                                       : Vl + vbase;
    ushort_t* lsel = (wave == 0) ? lsKh[0]
                   : (wave == 1) ? lsKl[0]
                   : (wave == 2) ? lsVh[0]
                                 : lsVl[0];
    const bool isK = wave < 2;
    const int sr = lane >> 3, sg = lane & 7;

#define STAGE(BUF, J0)                                                         \
    {                                                                          \
        ushort_t* dst_ = lsel + (BUF) * 4096;                                  \
        _Pragma("unroll") for (int i_ = 0; i_ < 8; ++i_) {                     \
            const ushort_t* s_ = isK                                           \
                ? gsel + (size_t)((J0) + i_ * 8 + sr) * DHEAD + sg * 8         \
                : gsel + (size_t)(i_ * 8 + sr) * NN + (J0) + sg * 8;           \
            GLDS(s_, dst_ + i_ * 512);                                         \
        }                                                                      \
    }

    f32x16 o0, o1, zz;
#pragma unroll
    for (int r = 0; r < 16; ++r) { o0[r] = 0.f; o1[r] = 0.f; zz[r] = 0.f; }
    float m = -1e30f, l = 0.f;

    STAGE(0, 0);
    __syncthreads();

#pragma unroll 1
    for (int t = 0; t < NN / 64; ++t) {
        const int buf = t & 1;
        if (t < NN / 64 - 1) STAGE(buf ^ 1, (t + 1) * 64);

#pragma unroll
        for (int js = 0; js < 2; ++js) {
            // K fragments from LDS (swizzled)
            bf16x8 kh_[4], kl_[4];
            const int kro = (js * 32 + l31) * 64;
#pragma unroll
            for (int c = 0; c < 4; ++c) {
                const int go = ((2 * c + hi5) ^ r7) * 8;
                kh_[c] = *(const bf16x8*)(lsKh[buf] + kro + go);
                kl_[c] = *(const bf16x8*)(lsKl[buf] + kro + go);
            }
            // QK^T: two independent 6-deep chains
            f32x16 sA = mfma32(kh_[0], qfh[0], zz);
            sA = mfma32(kl_[0], qfh[0], sA);
            sA = mfma32(kh_[0], qfl[0], sA);
            sA = mfma32(kh_[1], qfh[1], sA);
            sA = mfma32(kl_[1], qfh[1], sA);
            sA = mfma32(kh_[1], qfl[1], sA);
            f32x16 sB = mfma32(kh_[2], qfh[2], zz);
            sB = mfma32(kl_[2], qfh[2], sB);
            sB = mfma32(kh_[2], qfl[2], sB);
            sB = mfma32(kh_[3], qfh[3], sB);
            sB = mfma32(kl_[3], qfh[3], sB);
            sB = mfma32(kh_[3], qfl[3], sB);
            f32x16 s;
#pragma unroll
            for (int r = 0; r < 16; ++r) s[r] = sA[r] + sB[r];

            float tmA = fmaxf(fmaxf(fmaxf(s[0], s[1]), fmaxf(s[2], s[3])),
                              fmaxf(fmaxf(s[4], s[5]), fmaxf(s[6], s[7])));
            float tmB = fmaxf(fmaxf(fmaxf(s[8], s[9]), fmaxf(s[10], s[11])),
                              fmaxf(fmaxf(s[12], s[13]), fmaxf(s[14], s[15])));
            float tmax = fmaxf(tmA, tmB);
            tmax = fmaxf(tmax, __shfl_xor(tmax, 32));
            if (!__all(tmax - m <= 8.0f)) {
                float mn = fmaxf(m, tmax);
                float corr = __expf(m - mn);
                l *= corr;
#pragma unroll
                for (int r = 0; r < 16; ++r) { o0[r] *= corr; o1[r] *= corr; }
                m = mn;
            }
            float ps = 0.f;
#pragma unroll
            for (int r = 0; r < 16; ++r) {
                s[r] = __expf(s[r] - m);
                ps += s[r];
            }
            l += ps + __shfl_xor(ps, 32);

            // pack + blend-shuffle P redistribution; PV from LDS V
#pragma unroll
            for (int jc = 0; jc < 2; ++jc) {
                ushort_t h0 = f2bf(s[8 * jc + 0]), h1 = f2bf(s[8 * jc + 1]);
                ushort_t h2 = f2bf(s[8 * jc + 2]), h3 = f2bf(s[8 * jc + 3]);
                ushort_t h4 = f2bf(s[8 * jc + 4]), h5 = f2bf(s[8 * jc + 5]);
                ushort_t h6 = f2bf(s[8 * jc + 6]), h7 = f2bf(s[8 * jc + 7]);
                unsigned P0 = (unsigned)h0 | ((unsigned)h1 << 16);
                unsigned P1 = (unsigned)h2 | ((unsigned)h3 << 16);
                unsigned P2 = (unsigned)h4 | ((unsigned)h5 << 16);
                unsigned P3 = (unsigned)h6 | ((unsigned)h7 << 16);
                unsigned L0 = (unsigned)f2bf(s[8 * jc + 0] - bf2f(h0)) |
                              ((unsigned)f2bf(s[8 * jc + 1] - bf2f(h1)) << 16);
                unsigned L1 = (unsigned)f2bf(s[8 * jc + 2] - bf2f(h2)) |
                              ((unsigned)f2bf(s[8 * jc + 3] - bf2f(h3)) << 16);
                unsigned L2 = (unsigned)f2bf(s[8 * jc + 4] - bf2f(h4)) |
                              ((unsigned)f2bf(s[8 * jc + 5] - bf2f(h5)) << 16);
                unsigned L3 = (unsigned)f2bf(s[8 * jc + 6] - bf2f(h6)) |
                              ((unsigned)f2bf(s[8 * jc + 7] - bf2f(h7)) << 16);
                unsigned ta = hi5 ? P0 : P2, tb = hi5 ? P1 : P3;
                unsigned ua = hi5 ? L0 : L2, ub = hi5 ? L1 : L3;
                unsigned sa = __shfl_xor((int)ta, 32), sb = __shfl_xor((int)tb, 32);
                unsigned va = __shfl_xor((int)ua, 32), vb = __shfl_xor((int)ub, 32);
                U4 th, tl;
                th.u[0] = hi5 ? sa : P0; th.u[1] = hi5 ? sb : P1;
                th.u[2] = hi5 ? P2 : sa; th.u[3] = hi5 ? P3 : sb;
                tl.u[0] = hi5 ? va : L0; tl.u[1] = hi5 ? vb : L1;
                tl.u[2] = hi5 ? L2 : va; tl.u[3] = hi5 ? L3 : vb;
                bf16x8 pBh = th.v, pBl = tl.v;
#pragma unroll
                for (int dt = 0; dt < 2; ++dt) {
                    const int vro = (dt * 32 + l31) * 64;
                    const int vgo = ((js * 4 + jc * 2 + hi5) ^ r7) * 8;
                    bf16x8 vh_ = *(const bf16x8*)(lsVh[buf] + vro + vgo);
                    bf16x8 vl_ = *(const bf16x8*)(lsVl[buf] + vro + vgo);
                    if (dt == 0) {
                        o0 = mfma32(vh_, pBh, o0);
                        o0 = mfma32(vh_, pBl, o0);
                        o0 = mfma32(vl_, pBh, o0);
                    } else {
                        o1 = mfma32(vh_, pBh, o1);
                        o1 = mfma32(vh_, pBl, o1);
                        o1 = mfma32(vl_, pBh, o1);
                    }
                }
            }
        }
        __syncthreads();
    }
#undef STAGE

    // epilogue: write transposed hi/lo bf16 aot[b][n][h*64+d]
    const float invl = 1.0f / l;
    const size_t rowb = ((size_t)b * NN + q0 + l31) * HDIM + h * DHEAD;
#pragma unroll
    for (int dt = 0; dt < 2; ++dt)
#pragma unroll
        for (int g = 0; g < 4; ++g) {
            ushort4v hv, lv;
#pragma unroll
            for (int i = 0; i < 4; ++i) {
                float f = (dt ? o1[4 * g + i] : o0[4 * g + i]) * invl;
                ushort_t h2 = f2bf(f);
                hv[i] = h2;
                lv[i] = f2bf(f - bf2f(h2));
            }
            size_t o = rowb + dt * 32 + 8 * g + 4 * hi5;
            *(ushort4v*)(aoth + o) = hv;
            *(ushort4v*)(aotl + o) = lv;
        }
}

// ---------------- launch ----------------
extern "C" void kernel_launch(void* const* d_in, const int* in_sizes, int n_in,
                              void* d_out, int out_size, void* d_ws, size_t ws_size,
                              hipStream_t stream) {
    const float* x     = (const float*)d_in[0];
    const float* w_qkv = (const float*)d_in[1];
    const float* w_out = (const float*)d_in[2];
    const float* b_out = (const float*)d_in[3];
    float* out = (float*)d_out;

    ushort_t* ws_u = (ushort_t*)d_ws;
    ushort_t* Qh = ws_u;
    ushort_t* Ql = Qh + QSZ;
    ushort_t* Kh = Ql + QSZ;
    ushort_t* Kl = Kh + QSZ;
    ushort_t* Vh = Kl + QSZ;
    ushort_t* Vl = Vh + QSZ;
    ushort_t* shared_u = ws_u + 6 * QSZ;
    ushort_t* wqh = shared_u;
    ushort_t* wql = wqh + (size_t)O3 * CIN;
    ushort_t* aoth = shared_u;
    ushort_t* aotl = aoth + (size_t)BATCH * NN * HDIM;
    ushort_t* woh = ws_u;
    ushort_t* wol = woh + (size_t)CIN * HDIM;
    ushort_t* xth = (ushort_t*)d_out;
    ushort_t* xtl = xth + (size_t)BATCH * NN * CIN;

    if (ws_size < (6 * QSZ + 2 * (size_t)BATCH * NN * CIN) * sizeof(ushort_t)) return;

    // 1) weight + input conversions
    convert_split<<<1536, 256, 0, stream>>>(w_qkv, wqh, wql, O3 * CIN / 8);
    transpose_cvt<<<dim3(NN / 32, CIN / 32, BATCH), 256, 0, stream>>>(x, xth, xtl);

    // 2) QKV projection -> Q plain, K/V swizzled hi/lo
    gemm_mfma<0><<<dim3(NN / 128, O3 / 128, BATCH), 256, 0, stream>>>(
        wqh, wql, xth, xtl, nullptr, nullptr, Qh, Ql, Kh, Kl, Vh, Vl);

    // 3) flash attention (LDS-staged, 512 blocks) -> aot hi/lo [b][n][ch]
    attn_mfma<<<dim3(512), 256, 0, stream>>>(
        Qh, Ql, Kh, Kl, Vh, Vl, aoth, aotl);

    // 4) w_out conversion into dead Q region
    convert_split<<<512, 256, 0, stream>>>(w_out, woh, wol, CIN * HDIM / 8);

    // 5) output projection + bias -> out f32
    gemm_mfma<1><<<dim3(NN / 128, HDIM / 128, BATCH), 256, 0, stream>>>(
        woh, wol, aoth, aotl, b_out, out, nullptr, nullptr, nullptr, nullptr,
        nullptr, nullptr);
}

// Round 7
// 260.373 us; speedup vs baseline: 1.7317x; 1.0330x over previous
//
#include <hip/hip_runtime.h>
#include <hip/hip_bf16.h>

// Problem constants
#define BATCH 2
#define CIN   1024
#define NN    2048
#define HEADS 16
#define DHEAD 64
#define HDIM  1024
#define O3    3072
#define QSCALE 0.125f
// 0.125 * log2(e): Q pre-scale so softmax runs in exp2 domain
#define QSCALE_L2E 0.18033688011112042f
#define QSZ ((size_t)BATCH * HEADS * NN * DHEAD)  // 4,194,304 elements

typedef unsigned short ushort_t;
typedef __attribute__((ext_vector_type(8))) short bf16x8;
typedef __attribute__((ext_vector_type(8))) unsigned short ushort8;
typedef __attribute__((ext_vector_type(4))) unsigned short ushort4v;
typedef __attribute__((ext_vector_type(16))) float f32x16;

__device__ inline ushort_t f2bf(float f) {
    unsigned u = __builtin_bit_cast(unsigned, f);
    unsigned r = u + 0x7fffu + ((u >> 16) & 1u);
    return (ushort_t)(r >> 16);
}
__device__ inline float bf2f(ushort_t h) {
    return __builtin_bit_cast(float, (unsigned)h << 16);
}
__device__ inline f32x16 mfma32(bf16x8 a, bf16x8 b, f32x16 c) {
    return __builtin_amdgcn_mfma_f32_32x32x16_bf16(a, b, c, 0, 0, 0);
}
// packed 2xbf16 (RNE): low half = bf16(a), high half = bf16(b)
__device__ inline unsigned cvt_pk_bf16(float a, float b) {
    unsigned r;
    asm("v_cvt_pk_bf16_f32 %0, %1, %2" : "=v"(r) : "v"(a), "v"(b));
    return r;
}
__device__ inline float lo_f(unsigned p) {
    return __builtin_bit_cast(float, p << 16);
}
__device__ inline float hi_f(unsigned p) {
    return __builtin_bit_cast(float, p & 0xffff0000u);
}

union U4 { unsigned u[4]; bf16x8 v; };

// global -> LDS direct (16B per lane); LDS dest is wave-uniform base + lane*16
#define GLDS(gp, lp) __builtin_amdgcn_global_load_lds( \
    (__attribute__((address_space(1))) void*)(gp),     \
    (__attribute__((address_space(3))) void*)(lp), 16, 0, 0)

// ---------------- elementwise f32 -> bf16 hi/lo split ----------------
__global__ __launch_bounds__(256) void convert_split(const float* __restrict__ in,
                                                     ushort_t* __restrict__ hi,
                                                     ushort_t* __restrict__ lo,
                                                     int n8) {
    int t = blockIdx.x * 256 + threadIdx.x;
    if (t >= n8) return;
    size_t base = (size_t)t * 8;
    float4 a = *(const float4*)(in + base);
    float4 b = *(const float4*)(in + base + 4);
    float v[8] = {a.x, a.y, a.z, a.w, b.x, b.y, b.z, b.w};
    ushort8 hv, lv;
#pragma unroll
    for (int i = 0; i < 8; ++i) {
        ushort_t h = f2bf(v[i]);
        hv[i] = h;
        lv[i] = f2bf(v[i] - bf2f(h));
    }
    *(ushort8*)(hi + base) = hv;
    *(ushort8*)(lo + base) = lv;
}

// ------------- transpose + split: in f32 [B][CIN][NN] -> out hi/lo [B][NN][CIN] -------------
__global__ __launch_bounds__(256) void transpose_cvt(const float* __restrict__ in,
                                                     ushort_t* __restrict__ th,
                                                     ushort_t* __restrict__ tl) {
    __shared__ float T[32][33];
    const int b = blockIdx.z;
    const int n0 = blockIdx.x * 32, c0 = blockIdx.y * 32;
    const int t = threadIdx.x;
    const int r = t >> 3, q = t & 7;
    float4 v = *(const float4*)(in + ((size_t)b * CIN + c0 + r) * NN + n0 + q * 4);
    T[r][q * 4 + 0] = v.x; T[r][q * 4 + 1] = v.y;
    T[r][q * 4 + 2] = v.z; T[r][q * 4 + 3] = v.w;
    __syncthreads();
    ushort4v hv, lv;
#pragma unroll
    for (int i = 0; i < 4; ++i) {
        float f = T[q * 4 + i][r];
        ushort_t h = f2bf(f);
        hv[i] = h;
        lv[i] = f2bf(f - bf2f(h));
    }
    size_t o = ((size_t)b * NN + n0 + r) * CIN + c0 + q * 4;
    *(ushort4v*)(th + o) = hv;
    *(ushort4v*)(tl + o) = lv;
}

// ---------------- MFMA split-bf16 GEMM ----------------
// MODE 0: QKV epilogue. Q: [bh][n][64] plain, scaled by 0.125*log2e.
// K: granule^(row&7) swizzled. V: [b*1024+ch][n], n-granule^(ch&7) swizzled.
// MODE 1: f32 out + bias
template<int MODE>
__global__ __launch_bounds__(256, 3) void gemm_mfma(
    const ushort_t* __restrict__ Ah, const ushort_t* __restrict__ Al,
    const ushort_t* __restrict__ Bth, const ushort_t* __restrict__ Btl,
    const float* __restrict__ bias, float* __restrict__ outF,
    ushort_t* __restrict__ Qh, ushort_t* __restrict__ Ql,
    ushort_t* __restrict__ Kh, ushort_t* __restrict__ Kl,
    ushort_t* __restrict__ Vh, ushort_t* __restrict__ Vl) {

    __shared__ __align__(16) ushort_t lsAh[4096], lsAl[4096], lsBh[4096], lsBl[4096];

    const int b  = blockIdx.z;
    const int n0 = blockIdx.x * 128;
    const int m0 = blockIdx.y * 128;
    const int tid = threadIdx.x;
    const int wave = tid >> 6, lane = tid & 63;
    const int l31 = lane & 31, hi5 = lane >> 5;
    const int wr = wave >> 1, wc = wave & 1;

    const int srow = lane >> 2;
    const int kswz = 8 * ((lane & 3) ^ ((lane >> 3) & 3));
    const ushort_t* gAh = Ah  + (size_t)(m0 + wave * 16 + srow) * CIN + kswz;
    const ushort_t* gAl = Al  + (size_t)(m0 + wave * 16 + srow) * CIN + kswz;
    const ushort_t* gBh = Bth + ((size_t)b * NN + n0 + wave * 16 + srow) * CIN + kswz;
    const ushort_t* gBl = Btl + ((size_t)b * NN + n0 + wave * 16 + srow) * CIN + kswz;
    ushort_t* dAh = lsAh + wave * 512;
    ushort_t* dAl = lsAl + wave * 512;
    ushort_t* dBh = lsBh + wave * 512;
    ushort_t* dBl = lsBl + wave * 512;

    const int rswz = ((l31 >> 1) & 3) * 8;
    int offA[2][2], offB[2][2];
#pragma unroll
    for (int f = 0; f < 2; ++f)
#pragma unroll
        for (int kh = 0; kh < 2; ++kh) {
            offA[f][kh] = (wr * 64 + f * 32 + l31) * 64 + ((kh * 16 + hi5 * 8) ^ rswz) * 2;
            offB[f][kh] = (wc * 64 + f * 32 + l31) * 64 + ((kh * 16 + hi5 * 8) ^ rswz) * 2;
        }

    f32x16 acc[2][2];
#pragma unroll
    for (int i = 0; i < 2; ++i)
#pragma unroll
        for (int j = 0; j < 2; ++j)
#pragma unroll
            for (int r = 0; r < 16; ++r) acc[i][j][r] = 0.f;

    for (int k0 = 0; k0 < CIN; k0 += 32) {
        __syncthreads();
        GLDS(gAh + k0,            dAh);
        GLDS(gAh + 64 * CIN + k0, dAh + 2048);
        GLDS(gAl + k0,            dAl);
        GLDS(gAl + 64 * CIN + k0, dAl + 2048);
        GLDS(gBh + k0,            dBh);
        GLDS(gBh + 64 * CIN + k0, dBh + 2048);
        GLDS(gBl + k0,            dBl);
        GLDS(gBl + 64 * CIN + k0, dBl + 2048);
        __syncthreads();
#pragma unroll
        for (int kh = 0; kh < 2; ++kh) {
            bf16x8 a_h[2], a_l[2], b_h[2], b_l[2];
#pragma unroll
            for (int f = 0; f < 2; ++f) {
                a_h[f] = *(const bf16x8*)((const char*)lsAh + offA[f][kh]);
                a_l[f] = *(const bf16x8*)((const char*)lsAl + offA[f][kh]);
                b_h[f] = *(const bf16x8*)((const char*)lsBh + offB[f][kh]);
                b_l[f] = *(const bf16x8*)((const char*)lsBl + offB[f][kh]);
            }
#pragma unroll
            for (int fi = 0; fi < 2; ++fi)
#pragma unroll
                for (int fj = 0; fj < 2; ++fj) {
                    acc[fi][fj] = mfma32(a_l[fi], b_h[fj], acc[fi][fj]);
                    acc[fi][fj] = mfma32(a_h[fi], b_l[fj], acc[fi][fj]);
                    acc[fi][fj] = mfma32(a_h[fi], b_h[fj], acc[fi][fj]);
                }
        }
    }

    const int nn = n0 + wc * 64 + l31;

    if constexpr (MODE == 0) {
        const int region = m0 >> 10;  // 0=Q 1=K 2=V (uniform per block)
        if (region < 2) {
            const float scale = (region == 0) ? QSCALE_L2E : 1.0f;
            ushort_t* H = (region == 0) ? Qh : Kh;
            ushort_t* L = (region == 0) ? Ql : Kl;
            const int head = ((m0 & 1023) >> 6) + wr;
            const size_t bh_base = (size_t)(b * HEADS + head) * NN;
#pragma unroll
            for (int fj = 0; fj < 2; ++fj) {
                const size_t rowb = (bh_base + nn + fj * 32) * DHEAD;
#pragma unroll
                for (int fi = 0; fi < 2; ++fi) {
#pragma unroll
                    for (int g = 0; g < 4; ++g) {
                        ushort4v hv, lv;
#pragma unroll
                        for (int i = 0; i < 4; ++i) {
                            float f = acc[fi][fj][4 * g + i] * scale;
                            ushort_t h2 = f2bf(f);
                            hv[i] = h2;
                            lv[i] = f2bf(f - bf2f(h2));
                        }
                        // K gets granule swizzle ^(row&7); row&7 == l31&7
                        const int e = (region == 1)
                            ? (((fi * 4 + g) ^ (l31 & 7)) * 8 + 4 * hi5)
                            : (fi * 32 + 4 * hi5 + 8 * g);
                        *(ushort4v*)(H + rowb + e) = hv;
                        *(ushort4v*)(L + rowb + e) = lv;
                    }
                }
            }
        } else {
            const int ch0 = (m0 - 2048) + wr * 64;
#pragma unroll
            for (int fi = 0; fi < 2; ++fi)
#pragma unroll
                for (int fj = 0; fj < 2; ++fj)
#pragma unroll
                    for (int r = 0; r < 16; ++r) {
                        const int ch = ch0 + fi * 32 + (r & 3) + 8 * (r >> 2) + 4 * hi5;
                        const int g6 = (fj * 4 + (l31 >> 3)) ^ ((r & 3) + 4 * hi5);
                        const int n_ = n0 + wc * 64 + g6 * 8 + (l31 & 7);
                        const size_t idx = ((size_t)b * HDIM + ch) * NN + n_;
                        float f = acc[fi][fj][r];
                        ushort_t h2 = f2bf(f);
                        Vh[idx] = h2;
                        Vl[idx] = f2bf(f - bf2f(h2));
                    }
        }
    } else {
#pragma unroll
        for (int fi = 0; fi < 2; ++fi)
#pragma unroll
            for (int fj = 0; fj < 2; ++fj)
#pragma unroll
                for (int r = 0; r < 16; ++r) {
                    const int mrow = m0 + wr * 64 + fi * 32 + (r & 3) + 8 * (r >> 2) + 4 * hi5;
                    outF[((size_t)b * CIN + mrow) * NN + nn + fj * 32] =
                        acc[fi][fj][r] + bias[mrow];
                }
    }
}

// ---------------- MFMA flash attention: LDS-staged K/V, double-buffered ----------------
__global__ __launch_bounds__(256, 2) void attn_mfma(
    const ushort_t* __restrict__ Qh, const ushort_t* __restrict__ Ql,
    const ushort_t* __restrict__ Kh, const ushort_t* __restrict__ Kl,
    const ushort_t* __restrict__ Vh, const ushort_t* __restrict__ Vl,
    ushort_t* __restrict__ aoth, ushort_t* __restrict__ aotl) {
    // grid 512 = 8 xcd-slots x 4 bh x 16 qtiles (K/V of 4 heads ~ one L2)
    const int Lid = blockIdx.x;
    const int slot = Lid & 7, rest = Lid >> 3;
    const int bh = slot * 4 + (rest >> 4);
    const int qt = rest & 15;
    const int b = bh >> 4, h = bh & 15;
    const int wave = threadIdx.x >> 6;
    const int lane = threadIdx.x & 63;
    const int l31 = lane & 31;
    const int hi5 = lane >> 5;
    const int r7 = l31 & 7;
    const int q0 = qt * 128 + wave * 32;

    __shared__ __align__(16) ushort_t lsKh[2][4096], lsKl[2][4096];
    __shared__ __align__(16) ushort_t lsVh[2][4096], lsVl[2][4096];

    bf16x8 qfh[4], qfl[4];
    {
        const ushort_t* qb  = Qh + ((size_t)bh * NN + q0 + l31) * DHEAD + hi5 * 8;
        const ushort_t* qlb = Ql + ((size_t)bh * NN + q0 + l31) * DHEAD + hi5 * 8;
#pragma unroll
        for (int c = 0; c < 4; ++c) {
            qfh[c] = *(const bf16x8*)(qb + c * 16);
            qfl[c] = *(const bf16x8*)(qlb + c * 16);
        }
    }

    const size_t kbase = (size_t)bh * NN * DHEAD;
    const size_t vbase = (size_t)bh * DHEAD * NN;
    const ushort_t* gsel = (wave == 0) ? Kh + kbase
                         : (wave == 1) ? Kl + kbase
                         : (wave == 2) ? Vh + vbase
                                       : Vl + vbase;
    ushort_t* lsel = (wave == 0) ? lsKh[0]
                   : (wave == 1) ? lsKl[0]
                   : (wave == 2) ? lsVh[0]
                                 : lsVl[0];
    const bool isK = wave < 2;
    const int sr = lane >> 3, sg = lane & 7;

#define STAGE(BUF, J0)                                                         \
    {                                                                          \
        ushort_t* dst_ = lsel + (BUF) * 4096;                                  \
        _Pragma("unroll") for (int i_ = 0; i_ < 8; ++i_) {                     \
            const ushort_t* s_ = isK                                           \
                ? gsel + (size_t)((J0) + i_ * 8 + sr) * DHEAD + sg * 8         \
                : gsel + (size_t)(i_ * 8 + sr) * NN + (J0) + sg * 8;           \
            GLDS(s_, dst_ + i_ * 512);                                         \
        }                                                                      \
    }

    f32x16 o0, o1, zz;
#pragma unroll
    for (int r = 0; r < 16; ++r) { o0[r] = 0.f; o1[r] = 0.f; zz[r] = 0.f; }
    float m = -1e30f, l = 0.f;

    STAGE(0, 0);
    __syncthreads();

#pragma unroll 1
    for (int t = 0; t < NN / 64; ++t) {
        const int buf = t & 1;
        if (t < NN / 64 - 1) STAGE(buf ^ 1, (t + 1) * 64);

#pragma unroll
        for (int js = 0; js < 2; ++js) {
            bf16x8 kh_[4], kl_[4];
            const int kro = (js * 32 + l31) * 64;
#pragma unroll
            for (int c = 0; c < 4; ++c) {
                const int go = ((2 * c + hi5) ^ r7) * 8;
                kh_[c] = *(const bf16x8*)(lsKh[buf] + kro + go);
                kl_[c] = *(const bf16x8*)(lsKl[buf] + kro + go);
            }
            __builtin_amdgcn_s_setprio(1);
            f32x16 sA = mfma32(kh_[0], qfh[0], zz);
            sA = mfma32(kl_[0], qfh[0], sA);
            sA = mfma32(kh_[0], qfl[0], sA);
            sA = mfma32(kh_[1], qfh[1], sA);
            sA = mfma32(kl_[1], qfh[1], sA);
            sA = mfma32(kh_[1], qfl[1], sA);
            f32x16 sB = mfma32(kh_[2], qfh[2], zz);
            sB = mfma32(kl_[2], qfh[2], sB);
            sB = mfma32(kh_[2], qfl[2], sB);
            sB = mfma32(kh_[3], qfh[3], sB);
            sB = mfma32(kl_[3], qfh[3], sB);
            sB = mfma32(kh_[3], qfl[3], sB);
            __builtin_amdgcn_s_setprio(0);
            f32x16 s;
#pragma unroll
            for (int r = 0; r < 16; ++r) s[r] = sA[r] + sB[r];

            float tmA = fmaxf(fmaxf(fmaxf(s[0], s[1]), fmaxf(s[2], s[3])),
                              fmaxf(fmaxf(s[4], s[5]), fmaxf(s[6], s[7])));
            float tmB = fmaxf(fmaxf(fmaxf(s[8], s[9]), fmaxf(s[10], s[11])),
                              fmaxf(fmaxf(s[12], s[13]), fmaxf(s[14], s[15])));
            float tmax = fmaxf(tmA, tmB);
            tmax = fmaxf(tmax, __shfl_xor(tmax, 32));
            // defer-max: 8 nats = 11.54 bits in exp2 domain
            if (!__all(tmax - m <= 11.5f)) {
                float mn = fmaxf(m, tmax);
                float corr = __builtin_amdgcn_exp2f(m - mn);
                l *= corr;
#pragma unroll
                for (int r = 0; r < 16; ++r) { o0[r] *= corr; o1[r] *= corr; }
                m = mn;
            }
            float ps = 0.f;
#pragma unroll
            for (int r = 0; r < 16; ++r) {
                s[r] = __builtin_amdgcn_exp2f(s[r] - m);
                ps += s[r];
            }
            l += ps + __shfl_xor(ps, 32);

            // pack via v_cvt_pk_bf16_f32 + blend-shuffle redistribution; PV
#pragma unroll
            for (int jc = 0; jc < 2; ++jc) {
                unsigned P0 = cvt_pk_bf16(s[8 * jc + 0], s[8 * jc + 1]);
                unsigned P1 = cvt_pk_bf16(s[8 * jc + 2], s[8 * jc + 3]);
                unsigned P2 = cvt_pk_bf16(s[8 * jc + 4], s[8 * jc + 5]);
                unsigned P3 = cvt_pk_bf16(s[8 * jc + 6], s[8 * jc + 7]);
                unsigned L0 = cvt_pk_bf16(s[8 * jc + 0] - lo_f(P0),
                                          s[8 * jc + 1] - hi_f(P0));
                unsigned L1 = cvt_pk_bf16(s[8 * jc + 2] - lo_f(P1),
                                          s[8 * jc + 3] - hi_f(P1));
                unsigned L2 = cvt_pk_bf16(s[8 * jc + 4] - lo_f(P2),
                                          s[8 * jc + 5] - hi_f(P2));
                unsigned L3 = cvt_pk_bf16(s[8 * jc + 6] - lo_f(P3),
                                          s[8 * jc + 7] - hi_f(P3));
                unsigned ta = hi5 ? P0 : P2, tb = hi5 ? P1 : P3;
                unsigned ua = hi5 ? L0 : L2, ub = hi5 ? L1 : L3;
                unsigned sa = __shfl_xor((int)ta, 32), sb = __shfl_xor((int)tb, 32);
                unsigned va = __shfl_xor((int)ua, 32), vb = __shfl_xor((int)ub, 32);
                U4 th, tl;
                th.u[0] = hi5 ? sa : P0; th.u[1] = hi5 ? sb : P1;
                th.u[2] = hi5 ? P2 : sa; th.u[3] = hi5 ? P3 : sb;
                tl.u[0] = hi5 ? va : L0; tl.u[1] = hi5 ? vb : L1;
                tl.u[2] = hi5 ? L2 : va; tl.u[3] = hi5 ? L3 : vb;
                bf16x8 pBh = th.v, pBl = tl.v;
#pragma unroll
                for (int dt = 0; dt < 2; ++dt) {
                    const int vro = (dt * 32 + l31) * 64;
                    const int vgo = ((js * 4 + jc * 2 + hi5) ^ r7) * 8;
                    bf16x8 vh_ = *(const bf16x8*)(lsVh[buf] + vro + vgo);
                    bf16x8 vl_ = *(const bf16x8*)(lsVl[buf] + vro + vgo);
                    __builtin_amdgcn_s_setprio(1);
                    if (dt == 0) {
                        o0 = mfma32(vh_, pBh, o0);
                        o0 = mfma32(vh_, pBl, o0);
                        o0 = mfma32(vl_, pBh, o0);
                    } else {
                        o1 = mfma32(vh_, pBh, o1);
                        o1 = mfma32(vh_, pBl, o1);
                        o1 = mfma32(vl_, pBh, o1);
                    }
                    __builtin_amdgcn_s_setprio(0);
                }
            }
        }
        __syncthreads();
    }
#undef STAGE

    // epilogue: write transposed hi/lo bf16 aot[b][n][h*64+d]
    const float invl = 1.0f / l;
    const size_t rowb = ((size_t)b * NN + q0 + l31) * HDIM + h * DHEAD;
#pragma unroll
    for (int dt = 0; dt < 2; ++dt)
#pragma unroll
        for (int g = 0; g < 4; ++g) {
            ushort4v hv, lv;
#pragma unroll
            for (int i = 0; i < 4; ++i) {
                float f = (dt ? o1[4 * g + i] : o0[4 * g + i]) * invl;
                ushort_t h2 = f2bf(f);
                hv[i] = h2;
                lv[i] = f2bf(f - bf2f(h2));
            }
            size_t o = rowb + dt * 32 + 8 * g + 4 * hi5;
            *(ushort4v*)(aoth + o) = hv;
            *(ushort4v*)(aotl + o) = lv;
        }
}

// ---------------- launch ----------------
extern "C" void kernel_launch(void* const* d_in, const int* in_sizes, int n_in,
                              void* d_out, int out_size, void* d_ws, size_t ws_size,
                              hipStream_t stream) {
    const float* x     = (const float*)d_in[0];
    const float* w_qkv = (const float*)d_in[1];
    const float* w_out = (const float*)d_in[2];
    const float* b_out = (const float*)d_in[3];
    float* out = (float*)d_out;

    ushort_t* ws_u = (ushort_t*)d_ws;
    ushort_t* Qh = ws_u;
    ushort_t* Ql = Qh + QSZ;
    ushort_t* Kh = Ql + QSZ;
    ushort_t* Kl = Kh + QSZ;
    ushort_t* Vh = Kl + QSZ;
    ushort_t* Vl = Vh + QSZ;
    ushort_t* shared_u = ws_u + 6 * QSZ;
    ushort_t* wqh = shared_u;
    ushort_t* wql = wqh + (size_t)O3 * CIN;
    ushort_t* aoth = shared_u;
    ushort_t* aotl = aoth + (size_t)BATCH * NN * HDIM;
    ushort_t* woh = ws_u;
    ushort_t* wol = woh + (size_t)CIN * HDIM;
    ushort_t* xth = (ushort_t*)d_out;
    ushort_t* xtl = xth + (size_t)BATCH * NN * CIN;

    if (ws_size < (6 * QSZ + 2 * (size_t)BATCH * NN * CIN) * sizeof(ushort_t)) return;

    // 1) weight + input conversions
    convert_split<<<1536, 256, 0, stream>>>(w_qkv, wqh, wql, O3 * CIN / 8);
    transpose_cvt<<<dim3(NN / 32, CIN / 32, BATCH), 256, 0, stream>>>(x, xth, xtl);

    // 2) QKV projection -> Q (exp2-scaled) plain, K/V swizzled hi/lo
    gemm_mfma<0><<<dim3(NN / 128, O3 / 128, BATCH), 256, 0, stream>>>(
        wqh, wql, xth, xtl, nullptr, nullptr, Qh, Ql, Kh, Kl, Vh, Vl);

    // 3) flash attention (LDS-staged, 512 blocks) -> aot hi/lo [b][n][ch]
    attn_mfma<<<dim3(512), 256, 0, stream>>>(
        Qh, Ql, Kh, Kl, Vh, Vl, aoth, aotl);

    // 4) w_out conversion into dead Q region
    convert_split<<<512, 256, 0, stream>>>(w_out, woh, wol, CIN * HDIM / 8);

    // 5) output projection + bias -> out f32
    gemm_mfma<1><<<dim3(NN / 128, HDIM / 128, BATCH), 256, 0, stream>>>(
        woh, wol, aoth, aotl, b_out, out, nullptr, nullptr, nullptr, nullptr,
        nullptr, nullptr);
}